// Round 13
// baseline (1747.729 us; speedup 1.0000x reference)
//
#include <hip/hip_runtime.h>
#include <hip/hip_bf16.h>

typedef __hip_bfloat16 bf16;

#define BB 32   // batch
#define NN 16   // patches / backbones

__device__ __forceinline__ float b2f(bf16 v){ return __bfloat162float(v); }
__device__ __forceinline__ bf16  f2b(float v){ return __float2bfloat16(v); }
__device__ __forceinline__ float ldv(const float* p){ return *p; }
__device__ __forceinline__ float ldv(const bf16* p){ return b2f(*p); }
__device__ __forceinline__ void  stv(float* p, float v){ *p = v; }
__device__ __forceinline__ void  stv(bf16* p, float v){ *p = f2b(v); }

struct alignas(8) BF4 { bf16 a, b, c, d; };
__device__ __forceinline__ void stv4(float* p, float4 v){ *(float4*)p = v; }
__device__ __forceinline__ void stv4(bf16* p, float4 v){
    BF4 o; o.a = f2b(v.x); o.b = f2b(v.y); o.c = f2b(v.z); o.d = f2b(v.w);
    *(BF4*)p = o;
}

__device__ __forceinline__ float bfbits2f(unsigned int h){
    unsigned int x = h << 16; float f; __builtin_memcpy(&f, &x, 4); return f;
}
__device__ __forceinline__ float4 ldv4(const float* p){ return *(const float4*)p; }
__device__ __forceinline__ float4 ldv4(const bf16* p){
    uint2 u = *(const uint2*)p;
    float4 r;
    r.x = bfbits2f(u.x & 0xffffu);  r.y = bfbits2f(u.x >> 16);
    r.z = bfbits2f(u.y & 0xffffu);  r.w = bfbits2f(u.y >> 16);
    return r;
}

// ---------------------------------------------------------------------------
// dtype probe: flag=1 -> float32 inputs; 0 -> bf16.
// ---------------------------------------------------------------------------
__launch_bounds__(256)
__global__ void detect_ker(const unsigned short* __restrict__ xs, int* __restrict__ flag)
{
    int tid = threadIdx.x;
    int cnt = 0;
    for (int i = tid; i < 262144; i += 256) {
        unsigned short u = xs[i];
        if ((u & 0x7F80u) == 0x7F80u) cnt++;
    }
    #pragma unroll
    for (int off = 32; off > 0; off >>= 1) cnt += __shfl_down(cnt, off, 64);
    __shared__ int red[4];
    if ((tid & 63) == 0) red[tid >> 6] = cnt;
    __syncthreads();
    if (tid == 0) flag[0] = (red[0] + red[1] + red[2] + red[3]) > 0 ? 1 : 0;
}

// ---------------------------------------------------------------------------
// stage all inputs into a contiguous FLOAT arena
// ---------------------------------------------------------------------------
struct CvtArgs { const void* src[19]; int cnt[19]; int off[19]; };

__launch_bounds__(256)
__global__ void convert_ker(CvtArgs a, float* __restrict__ dst, const int* __restrict__ flag)
{
    const int which = blockIdx.y;
    const int cnt = a.cnt[which];
    if ((int)blockIdx.x * 2048 >= cnt) return;
    const int base = blockIdx.x * 2048 + threadIdx.x;
    float* d = dst + a.off[which];
    if (*flag) {
        const float* s = (const float*)a.src[which];
        #pragma unroll
        for (int k = 0; k < 8; ++k) { int j = base + k * 256; if (j < cnt) d[j] = s[j]; }
    } else {
        const bf16* s = (const bf16*)a.src[which];
        #pragma unroll
        for (int k = 0; k < 8; ++k) { int j = base + k * 256; if (j < cnt) d[j] = b2f(s[j]); }
    }
}

// ---------------------------------------------------------------------------
// weight transpose: [n][co][ci][9] -> [n][ci*9+j][co]  (co-major for float4)
// ---------------------------------------------------------------------------
template<int COUT, int CIN>
__launch_bounds__(256)
__global__ void wtrans_ker(const float* __restrict__ src, float* __restrict__ dst)
{
    const int per_n = COUT * CIN * 9;
    int i = blockIdx.x * 256 + threadIdx.x;
    if (i >= NN * per_n) return;
    int n = i / per_n, r = i - n * per_n;
    int co = r / (CIN * 9), k = r - co * (CIN * 9);
    dst[(size_t)n * per_n + k * COUT + co] = src[i];
}

// ---------------------------------------------------------------------------
// conv0: x -> a0 (bf16, written ONCE) + per-channel sum/sumsq atomics (f32).
// ---------------------------------------------------------------------------
__launch_bounds__(256)
__global__ void conv0w_ker(const float* __restrict__ x, const float* __restrict__ w,
                           bf16* __restrict__ a0, float* __restrict__ accum)
{
    constexpr int STRIP = 8, STRIPS = 8, IN_ROWS = 10, TW = 66;
    __shared__ float tile[3][IN_ROWS][TW];
    const int tid = threadIdx.x;
    const int bid = blockIdx.x;
    const int s = bid % STRIPS;
    const int b = (bid / STRIPS) % BB;
    const int n = bid / (STRIPS * BB);
    const int pr = (n >> 2) * 64, pc = (n & 3) * 64;
    const int r0 = s * STRIP - 1;

    for (int idx = tid; idx < 3 * IN_ROWS * TW; idx += 256) {
        int ci = idx / (IN_ROWS * TW);
        int rem = idx - ci * (IN_ROWS * TW);
        int rr = rem / TW, cc = rem - rr * TW;
        int gr = r0 + rr, gc = cc - 1;
        float v = 0.f;
        if (gr >= 0 && gr < 64 && gc >= 0 && gc < 64)
            v = x[((size_t)(b * 3 + ci) * 256 + (pr + gr)) * 256 + (pc + gc)];
        tile[ci][rr][cc] = v;
    }
    __syncthreads();

    const int xo = tid & 63;
    const int wv = tid >> 6;
    for (int pass = 0; pass < 2; ++pass) {
        const int co = (pass * 4 + wv) * 2;
        const float* wb = w + (size_t)((n * 16 + co) * 3) * 9;
        float acc0[STRIP], acc1[STRIP];
        #pragma unroll
        for (int r = 0; r < STRIP; ++r) { acc0[r] = 0.f; acc1[r] = 0.f; }
        #pragma unroll
        for (int ci = 0; ci < 3; ++ci) {
            float w0[9], w1[9];
            #pragma unroll
            for (int j = 0; j < 9; ++j) {
                w0[j] = wb[ci * 9 + j];
                w1[j] = wb[(3 + ci) * 9 + j];
            }
            float win[3][3];
            #pragma unroll
            for (int c0 = 0; c0 < 3; ++c0) {
                win[0][c0] = tile[ci][0][xo + c0];
                win[1][c0] = tile[ci][1][xo + c0];
            }
            #pragma unroll
            for (int ry = 0; ry < STRIP; ++ry) {
                #pragma unroll
                for (int c0 = 0; c0 < 3; ++c0)
                    win[(ry + 2) % 3][c0] = tile[ci][ry + 2][xo + c0];
                #pragma unroll
                for (int ky = 0; ky < 3; ++ky)
                    #pragma unroll
                    for (int kx = 0; kx < 3; ++kx) {
                        float v = win[(ry + ky) % 3][kx];
                        acc0[ry] = fmaf(v, w0[ky * 3 + kx], acc0[ry]);
                        acc1[ry] = fmaf(v, w1[ky * 3 + kx], acc1[ry]);
                    }
            }
        }
        bf16* ob = a0 + (size_t)((n * BB + b) * 16 + co) * 4096 + (s * STRIP) * 64 + xo;
        float s0 = 0.f, q0 = 0.f, s1 = 0.f, q1 = 0.f;
        #pragma unroll
        for (int r = 0; r < STRIP; ++r) {
            ob[r * 64] = f2b(acc0[r]);
            ob[4096 + r * 64] = f2b(acc1[r]);
            s0 += acc0[r]; q0 = fmaf(acc0[r], acc0[r], q0);
            s1 += acc1[r]; q1 = fmaf(acc1[r], acc1[r], q1);
        }
        #pragma unroll
        for (int off = 32; off > 0; off >>= 1) {
            s0 += __shfl_down(s0, off, 64); q0 += __shfl_down(q0, off, 64);
            s1 += __shfl_down(s1, off, 64); q1 += __shfl_down(q1, off, 64);
        }
        if (xo == 0) {
            atomicAdd(&accum[n * 16 + co],       s0);
            atomicAdd(&accum[256 + n * 16 + co], q0);
            atomicAdd(&accum[n * 16 + co + 1],       s1);
            atomicAdd(&accum[256 + n * 16 + co + 1], q1);
        }
    }
}

// ---------------------------------------------------------------------------
// generic coef finalize
// ---------------------------------------------------------------------------
template<int C, int HW>
__launch_bounds__(256)
__global__ void coeffin_ker(const float* __restrict__ accum, const float* __restrict__ hw,
                            float* __restrict__ coef)
{
    int i = blockIdx.x * 256 + threadIdx.x;   // n*C+c
    if (i >= NN * C) return;
    const float cnt = (float)(BB * HW);
    float mu = accum[i] / cnt;
    float var = fmaxf(accum[NN * C + i] / cnt - mu * mu, 0.f);
    float rs = rsqrtf(var + 1e-5f);
    int n = i / C, c = i - n * C;
    float w0 = hw[(n * 3 + 0) * C + c];
    float w1 = hw[(n * 3 + 1) * C + c];
    float w2 = hw[(n * 3 + 2) * C + c];
    float c2 = w2 * 0.70710678118654752440f;
    coef[i * 3 + 0] = (w0 - c2) - w1 * rs * mu + c2 * rs * rs * mu * mu;
    coef[i * 3 + 1] = w1 * rs - 2.f * c2 * rs * rs * mu;
    coef[i * 3 + 2] = c2 * rs * rs;
}

// ---------------------------------------------------------------------------
// generic fused herpn+conv3x3 (compact halo layout, vectorized staging,
// pipelined transposed weights, fused stats):
//  - STRIDE==1: 4-cols-per-thread mapping (xo4, rq, cq); per ci per row-group
//    1x ds_read_b32 + 2x ds_read_b128 feed 144 FMAs; float4 stores.
//  - STRIDE==2: previous per-column mapping.
// ---------------------------------------------------------------------------
template<typename TI, typename TO, int CIN, int COUT, int WIN, int WOUT, int STRIDE, int STRIP>
__launch_bounds__(256)
__global__ void conv_ker(const TI* __restrict__ ain, const float* __restrict__ coef,
                         const float* __restrict__ wT, TO* __restrict__ aout,
                         float* __restrict__ accum)
{
    constexpr int HIN = WIN, HOUT = WOUT;
    constexpr int STRIPS = HOUT / STRIP;
    constexpr int IN_ROWS = STRIDE * (STRIP - 1) + 3;
    constexpr int S = WIN + 4;               // compact row stride
    constexpr int TCO = 4;
    constexpr int L = WIN / 4;               // float4 chunks per row
    constexpr int RPI = 256 / L;             // rows staged per iteration
    constexpr int NROWS = CIN * IN_ROWS;
    static_assert(NROWS % RPI == 0, "staging divides evenly");
    static_assert(STRIDE != 1 || (WOUT * COUT == 1024 && STRIP == 8), "s1 mapping");
    static_assert(STRIDE != 2 || (256 / WOUT) * TCO == COUT, "s2 mapping");

    __shared__ float tile[NROWS * S + 4];
    __shared__ float cfA[CIN], cfB[CIN], cfC[CIN];

    const int tid = threadIdx.x;
    const int bid = blockIdx.x;
    const int s = bid % STRIPS;
    const int b = (bid / STRIPS) % BB;
    const int n = bid / (STRIPS * BB);

    if (tid < CIN) {
        cfA[tid] = coef[(n * CIN + tid) * 3 + 0];
        cfB[tid] = coef[(n * CIN + tid) * 3 + 1];
        cfC[tid] = coef[(n * CIN + tid) * 3 + 2];
    }
    __syncthreads();

    const int r0 = s * STRIP * STRIDE - 1;
    const TI* abase = ain + (size_t)(n * BB + b) * CIN * HIN * WIN;

    // halo zero
    for (int h = tid; h < NROWS * 2 + 1; h += 256) {
        if (h == NROWS * 2) tile[NROWS * S] = 0.f;
        else tile[(h >> 1) * S + ((h & 1) ? 3 : 0)] = 0.f;
    }
    // vectorized interior staging
    {
        const int li = tid % L;
        const int rs0 = tid / L;
        #pragma unroll
        for (int it = 0; it < NROWS / RPI; ++it) {
            int rslot = rs0 + it * RPI;
            int ci = rslot / IN_ROWS;
            int rr = rslot - ci * IN_ROWS;
            int gr = r0 + rr;
            float4 v = {0.f, 0.f, 0.f, 0.f};
            if (gr >= 0 && gr < HIN) {
                v = ldv4(&abase[(size_t)ci * HIN * WIN + gr * WIN + li * 4]);
                float Aq = cfA[ci], Bq = cfB[ci], Cq = cfC[ci];
                v.x = fmaf(v.x, fmaf(v.x, Cq, Bq), Aq);
                v.y = fmaf(v.y, fmaf(v.y, Cq, Bq), Aq);
                v.z = fmaf(v.z, fmaf(v.z, Cq, Bq), Aq);
                v.w = fmaf(v.w, fmaf(v.w, Cq, Bq), Aq);
            }
            *(float4*)&tile[rslot * S + 4 + li * 4] = v;
        }
    }
    __syncthreads();

    const float4* wb4 = (const float4*)(wT + (size_t)n * (CIN * 9 * COUT));

    if constexpr (STRIDE == 1) {
        constexpr int C4 = WOUT / 4;
        const int xo4 = tid % C4;
        const int rq  = (tid / C4) & 3;
        const int cq  = tid / (C4 * 4);

        float acc[4][2][TCO];   // [col][row-group][chan]
        #pragma unroll
        for (int c = 0; c < 4; ++c)
            #pragma unroll
            for (int g = 0; g < 2; ++g)
                #pragma unroll
                for (int t = 0; t < TCO; ++t) acc[c][g][t] = 0.f;

        auto conv_ci = [&](int ci, const float4 (&wq)[9]) {
            const float* wf = (const float*)&wq[0];
            #pragma unroll
            for (int g = 0; g < 2; ++g) {
                const int base = (ci * IN_ROWS + rq + g * 4) * S + 3 + 4 * xo4;
                float e[3][6];
                #pragma unroll
                for (int kr = 0; kr < 3; ++kr) {
                    const float* t = &tile[base + kr * S];
                    e[kr][0] = t[0];
                    float4 m = *(const float4*)(t + 1);
                    e[kr][1] = m.x; e[kr][2] = m.y; e[kr][3] = m.z; e[kr][4] = m.w;
                    e[kr][5] = t[5];
                }
                #pragma unroll
                for (int c = 0; c < 4; ++c)
                    #pragma unroll
                    for (int ky = 0; ky < 3; ++ky)
                        #pragma unroll
                        for (int kx = 0; kx < 3; ++kx) {
                            float v = e[ky][c + kx];
                            #pragma unroll
                            for (int t = 0; t < TCO; ++t)
                                acc[c][g][t] = fmaf(v, wf[(ky * 3 + kx) * 4 + t], acc[c][g][t]);
                        }
            }
        };

        float4 wqA[9], wqB[9];
        #pragma unroll
        for (int j = 0; j < 9; ++j) wqA[j] = wb4[j * (COUT / 4) + cq];
        for (int ci = 0; ci < CIN; ci += 2) {
            #pragma unroll
            for (int j = 0; j < 9; ++j) wqB[j] = wb4[((ci + 1) * 9 + j) * (COUT / 4) + cq];
            conv_ci(ci, wqA);
            if (ci + 2 < CIN) {
                #pragma unroll
                for (int j = 0; j < 9; ++j) wqA[j] = wb4[((ci + 2) * 9 + j) * (COUT / 4) + cq];
            }
            conv_ci(ci + 1, wqB);
        }

        const int co = cq * TCO;
        #pragma unroll
        for (int t = 0; t < TCO; ++t) {
            float ps = 0.f, pq = 0.f;
            #pragma unroll
            for (int g = 0; g < 2; ++g) {
                const int orow = s * STRIP + rq + g * 4;
                TO* ob = aout + (size_t)((n * BB + b) * COUT + co + t) * HOUT * WOUT
                         + orow * WOUT + 4 * xo4;
                float4 v4 = {acc[0][g][t], acc[1][g][t], acc[2][g][t], acc[3][g][t]};
                stv4(ob, v4);
                ps += v4.x + v4.y + v4.z + v4.w;
                pq = fmaf(v4.x, v4.x, pq); pq = fmaf(v4.y, v4.y, pq);
                pq = fmaf(v4.z, v4.z, pq); pq = fmaf(v4.w, v4.w, pq);
            }
            #pragma unroll
            for (int off = C4 * 2; off > 0; off >>= 1) {
                ps += __shfl_down(ps, off, C4 * 4); pq += __shfl_down(pq, off, C4 * 4);
            }
            if ((tid % (C4 * 4)) == 0) {
                atomicAdd(&accum[n * COUT + co + t], ps);
                atomicAdd(&accum[NN * COUT + n * COUT + co + t], pq);
            }
        }
    } else {
        const int xo = tid % WOUT;
        const int cq = tid / WOUT;
        float acc[TCO][STRIP];
        #pragma unroll
        for (int t = 0; t < TCO; ++t)
            #pragma unroll
            for (int r = 0; r < STRIP; ++r) acc[t][r] = 0.f;

        auto conv_ci = [&](int ci, const float4 (&wq)[9]) {
            const float* wf = (const float*)&wq[0];
            const float* tci = &tile[ci * IN_ROWS * S];
            #pragma unroll
            for (int ry = 0; ry < STRIP; ++ry)
                #pragma unroll
                for (int ky = 0; ky < 3; ++ky)
                    #pragma unroll
                    for (int kx = 0; kx < 3; ++kx) {
                        float v = tci[(ry * 2 + ky) * S + 3 + xo * 2 + kx];
                        #pragma unroll
                        for (int t = 0; t < TCO; ++t)
                            acc[t][ry] = fmaf(v, wf[(ky * 3 + kx) * 4 + t], acc[t][ry]);
                    }
        };

        float4 wqA[9], wqB[9];
        #pragma unroll
        for (int j = 0; j < 9; ++j) wqA[j] = wb4[j * (COUT / 4) + cq];
        for (int ci = 0; ci < CIN; ci += 2) {
            #pragma unroll
            for (int j = 0; j < 9; ++j) wqB[j] = wb4[((ci + 1) * 9 + j) * (COUT / 4) + cq];
            conv_ci(ci, wqA);
            if (ci + 2 < CIN) {
                #pragma unroll
                for (int j = 0; j < 9; ++j) wqA[j] = wb4[((ci + 2) * 9 + j) * (COUT / 4) + cq];
            }
            conv_ci(ci + 1, wqB);
        }

        const int co = cq * TCO;
        #pragma unroll
        for (int t = 0; t < TCO; ++t) {
            TO* ob = aout + (size_t)((n * BB + b) * COUT + co + t) * HOUT * WOUT
                     + (s * STRIP) * WOUT + xo;
            float ps = 0.f, pq = 0.f;
            #pragma unroll
            for (int r = 0; r < STRIP; ++r) {
                stv(&ob[r * WOUT], acc[t][r]);
                ps += acc[t][r]; pq = fmaf(acc[t][r], acc[t][r], pq);
            }
            #pragma unroll
            for (int off = WOUT / 2; off > 0; off >>= 1) {
                ps += __shfl_down(ps, off, WOUT); pq += __shfl_down(pq, off, WOUT);
            }
            if (xo == 0) {
                atomicAdd(&accum[n * COUT + co + t], ps);
                atomicAdd(&accum[NN * COUT + n * COUT + co + t], pq);
            }
        }
    }
}

// ---------------------------------------------------------------------------
// pool: herpn(a5) -> quadrant means -> y[N,B,256] (fp32)
// ---------------------------------------------------------------------------
template<typename TI>
__launch_bounds__(256)
__global__ void pool_ker(const TI* __restrict__ a5, const float* __restrict__ coef,
                         float* __restrict__ y)
{
    const int n = blockIdx.x / BB, b = blockIdx.x % BB;
    const int f = threadIdx.x;
    const int c = f >> 2, qh = (f >> 1) & 1, qw = f & 1;
    const TI* p = a5 + (size_t)((n * BB + b) * 64 + c) * 256;
    float A = coef[(n * 64 + c) * 3 + 0];
    float Bc = coef[(n * 64 + c) * 3 + 1];
    float Cc = coef[(n * 64 + c) * 3 + 2];
    float ssum = 0.f;
    for (int iy = 0; iy < 8; ++iy)
        for (int ix = 0; ix < 8; ++ix) {
            float raw = ldv(&p[(qh * 8 + iy) * 16 + (qw * 8 + ix)]);
            ssum += fmaf(raw, fmaf(raw, Cc, Bc), A);
        }
    y[(size_t)(n * BB + b) * 256 + f] = ssum * (1.f / 64.f);
}

// ---------------------------------------------------------------------------
// bn1: per (n,f) BN over B; writes batch-major yt[B][4096]
// ---------------------------------------------------------------------------
__launch_bounds__(256)
__global__ void bn1_ker(const float* __restrict__ y, const float* __restrict__ g,
                        const float* __restrict__ bta, float* __restrict__ yt)
{
    const int gid = blockIdx.x * 256 + threadIdx.x;   // n*256 + f
    const int n = gid >> 8;
    float s = 0.f, s2 = 0.f;
    for (int b = 0; b < BB; ++b) {
        float v = y[(size_t)((n * BB + b) * 256) + (gid & 255)];
        s += v;
        s2 = fmaf(v, v, s2);
    }
    float mu = s * (1.f / BB);
    float var = fmaxf(s2 * (1.f / BB) - mu * mu, 0.f);
    float rs = rsqrtf(var + 1e-5f);
    float gg = g[gid];
    float bb = bta[gid];
    for (int b = 0; b < BB; ++b) {
        float v = y[(size_t)((n * BB + b) * 256) + (gid & 255)];
        yt[(size_t)b * 4096 + gid] = fmaf((v - mu) * rs, gg, bb);
    }
}

// ---------------------------------------------------------------------------
// og head: column-parallel GEMM, 256 blocks (one per output col j)
// ---------------------------------------------------------------------------
__launch_bounds__(256)
__global__ void oghead_ker(const float* __restrict__ yt, const float* __restrict__ lin_w,
                           const float* __restrict__ lin_b, float* __restrict__ ograw)
{
    __shared__ float sw[4096];
    const int j = blockIdx.x;
    const float* wrow = lin_w + (size_t)j * 4096;
    for (int i = threadIdx.x; i < 4096; i += 256) sw[i] = wrow[i];
    __syncthreads();
    const int wv = threadIdx.x >> 6, ln = threadIdx.x & 63;
    const float bj = lin_b[j];
    for (int b = wv; b < BB; b += 4) {
        const float* yr = yt + (size_t)b * 4096;
        float a = 0.f;
        for (int i = ln; i < 4096; i += 64)
            a = fmaf(yr[i], sw[i], a);
        #pragma unroll
        for (int off = 32; off > 0; off >>= 1) a += __shfl_down(a, off, 64);
        if (ln == 0) ograw[b * 256 + j] = a + bj;
    }
}

// ---------------------------------------------------------------------------
// pred head
// ---------------------------------------------------------------------------
__launch_bounds__(256)
__global__ void pred_ker(const float* __restrict__ yt, const float* __restrict__ jig_w,
                         const float* __restrict__ jig_b, void* __restrict__ d_out,
                         const int* __restrict__ flag)
{
    __shared__ float sy[256];
    const int b = blockIdx.x >> 4, n = blockIdx.x & 15;
    sy[threadIdx.x] = yt[(size_t)b * 4096 + n * 256 + threadIdx.x];
    __syncthreads();
    const int k = threadIdx.x >> 4, part = threadIdx.x & 15;
    const float* wrow = jig_w + k * 256 + part * 16;
    const float* srow = sy + part * 16;
    float p = 0.f;
    #pragma unroll
    for (int t = 0; t < 16; ++t) p = fmaf(srow[t], wrow[t], p);
    #pragma unroll
    for (int off = 8; off > 0; off >>= 1) p += __shfl_down(p, off, 16);
    if (part == 0) {
        float v = p + jig_b[k];
        int pidx = 8192 + (b * 16 + n) * 16 + k;
        if (*flag) ((float*)d_out)[pidx] = v;
        else       ((bf16*)d_out)[pidx] = f2b(v);
    }
}

__launch_bounds__(256)
__global__ void ogbn_ker(const float* __restrict__ ograw, void* __restrict__ d_out,
                         const int* __restrict__ flag)
{
    const int j = threadIdx.x;
    float s = 0.f, s2 = 0.f;
    for (int b = 0; b < BB; ++b) {
        float v = ograw[b * 256 + j];
        s += v;
        s2 = fmaf(v, v, s2);
    }
    float mu = s * (1.f / BB);
    float var = fmaxf(s2 * (1.f / BB) - mu * mu, 0.f);
    float rs = rsqrtf(var + 1e-5f);
    const bool isf32 = (*flag != 0);
    for (int b = 0; b < BB; ++b) {
        float v = (ograw[b * 256 + j] - mu) * rs;
        if (isf32) ((float*)d_out)[b * 256 + j] = v;
        else       ((bf16*)d_out)[b * 256 + j] = f2b(v);
    }
    float t = (float)(j & 15);
    if (isf32) { ((float*)d_out)[16384 + j] = t; ((float*)d_out)[16640 + j] = t; }
    else       { ((bf16*)d_out)[16384 + j] = f2b(t); ((bf16*)d_out)[16640 + j] = f2b(t); }
}

// ---------------------------------------------------------------------------
extern "C" void kernel_launch(void* const* d_in, const int* in_sizes, int n_in,
                              void* d_out, int out_size, void* d_ws, size_t ws_size,
                              hipStream_t stream)
{
    char* wsb = (char*)d_ws;
    int*   flag   = (int*)wsb;                      // @0
    float* accumZ = (float*)(wsb + 4096);           // 7168 f stats accumulators
    float* coefs  = (float*)(wsb + 36864);          // 6*3072 f
    float* y      = (float*)(wsb + 131072);         // 131072 f
    float* yt     = (float*)(wsb + 655360);         // 131072 f  [B][4096]
    float* ograw  = (float*)(wsb + 1179648);        // 8192 f
    float* wTall  = (float*)(wsb + 1310720);        // transposed weights
    float* staged = (float*)(wsb + 6029312);        // f32 arena

    float* A0 = accumZ + 0;      // 512  (16ch)
    float* A1 = accumZ + 512;    // 512  (16ch)
    float* A2 = accumZ + 1024;   // 1024 (32ch)
    float* A3 = accumZ + 2048;   // 1024 (32ch)
    float* A4 = accumZ + 3072;   // 2048 (64ch)
    float* A5 = accumZ + 5120;   // 2048 (64ch)

    float* wt1 = wTall;                 // 16*2304
    float* wt2 = wt1 + 36864;           // 16*4608
    float* wt3 = wt2 + 73728;           // 16*9216
    float* wt4 = wt3 + 147456;          // 16*18432
    float* wt5 = wt4 + 294912;          // 16*36864

    CvtArgs ca;
    int off = 0, maxc = 0;
    for (int i = 0; i < 19; ++i) {
        ca.src[i] = d_in[i];
        ca.cnt[i] = in_sizes[i];
        ca.off[i] = off;
        off += in_sizes[i];
        if (in_sizes[i] > maxc) maxc = in_sizes[i];
    }
    float* sx      = staged + ca.off[0];
    float* scw0    = staged + ca.off[1];
    float* shw1    = staged + ca.off[2];
    float* scw1    = staged + ca.off[3];
    float* shw2    = staged + ca.off[4];
    float* scw2    = staged + ca.off[5];
    float* shw3    = staged + ca.off[6];
    float* scw3    = staged + ca.off[7];
    float* shw4    = staged + ca.off[8];
    float* scw4    = staged + ca.off[9];
    float* shw5    = staged + ca.off[10];
    float* scw5    = staged + ca.off[11];
    float* spool   = staged + ca.off[12];
    float* sg      = staged + ca.off[13];
    float* sb      = staged + ca.off[14];
    float* slin_w  = staged + ca.off[15];
    float* slin_b  = staged + ca.off[16];
    float* sjig_w  = staged + ca.off[17];
    float* sjig_b  = staged + ca.off[18];

    float* coef0 = coefs + 0 * 3072;
    float* coef1 = coefs + 1 * 3072;
    float* coef2 = coefs + 2 * 3072;
    float* coef3 = coefs + 3 * 3072;
    float* coef4 = coefs + 4 * 3072;
    float* coef5 = coefs + 5 * 3072;

    size_t stagedEnd = 6029312ull + (size_t)off * 4ull;
    size_t r1off = (stagedEnd + (1ull << 20)) & ~((1ull << 20) - 1ull);
    const bool planA = ws_size >= r1off + (128ull << 20) + (64ull << 20);

    detect_ker<<<1, 256, 0, stream>>>((const unsigned short*)d_in[0], flag);
    convert_ker<<<dim3((maxc + 2047) / 2048, 19), 256, 0, stream>>>(ca, staged, flag);

    wtrans_ker<16, 16><<<144, 256, 0, stream>>>(scw1, wt1);
    wtrans_ker<32, 16><<<288, 256, 0, stream>>>(scw2, wt2);
    wtrans_ker<32, 32><<<576, 256, 0, stream>>>(scw3, wt3);
    wtrans_ker<64, 32><<<1152, 256, 0, stream>>>(scw4, wt4);
    wtrans_ker<64, 64><<<2304, 256, 0, stream>>>(scw5, wt5);

    hipMemsetAsync(accumZ, 0, 7168 * sizeof(float), stream);

    if (planA) {
        float* rA = (float*)(wsb + r1off);
        char*  rB = wsb + r1off + (128ull << 20);
        bf16*  a0 = (bf16*)rB;          // 64 MiB
        float* a1 = rA;                 // 128 MiB
        float* a2 = (float*)rB;         // 64 MiB (a0 dead after conv1)
        float* a3 = rA;
        float* a4 = (float*)rB;
        float* a5 = rA;

        conv0w_ker<<<NN * BB * 8, 256, 0, stream>>>(sx, scw0, a0, A0);
        coeffin_ker<16, 4096><<<1, 256, 0, stream>>>(A0, shw1, coef0);
        conv_ker<bf16, float, 16, 16, 64, 64, 1, 8><<<NN * BB * 8, 256, 0, stream>>>(a0, coef0, wt1, a1, A1);
        coeffin_ker<16, 4096><<<1, 256, 0, stream>>>(A1, shw2, coef1);
        conv_ker<float, float, 16, 32, 64, 32, 2, 4><<<NN * BB * 8, 256, 0, stream>>>(a1, coef1, wt2, a2, A2);
        coeffin_ker<32, 1024><<<2, 256, 0, stream>>>(A2, shw3, coef2);
        conv_ker<float, float, 32, 32, 32, 32, 1, 8><<<NN * BB * 4, 256, 0, stream>>>(a2, coef2, wt3, a3, A3);
        coeffin_ker<32, 1024><<<2, 256, 0, stream>>>(A3, shw4, coef3);
        conv_ker<float, float, 32, 64, 32, 16, 2, 4><<<NN * BB * 4, 256, 0, stream>>>(a3, coef3, wt4, a4, A4);
        coeffin_ker<64, 256><<<4, 256, 0, stream>>>(A4, shw5, coef4);
        conv_ker<float, float, 64, 64, 16, 16, 1, 8><<<NN * BB * 2, 256, 0, stream>>>(a4, coef4, wt5, a5, A5);
        coeffin_ker<64, 256><<<4, 256, 0, stream>>>(A5, spool, coef5);
        pool_ker<float><<<NN * BB, 256, 0, stream>>>(a5, coef5, y);
    } else {
        char* rA = wsb + r1off;
        char* rB = wsb + r1off + (64ull << 20);
        bf16*  a0 = (bf16*)rB;
        bf16*  a1 = (bf16*)rA;
        bf16*  a2 = (bf16*)rB;
        float* a3 = (float*)rA;
        float* a4 = (float*)rB;
        float* a5 = (float*)rA;

        conv0w_ker<<<NN * BB * 8, 256, 0, stream>>>(sx, scw0, a0, A0);
        coeffin_ker<16, 4096><<<1, 256, 0, stream>>>(A0, shw1, coef0);
        conv_ker<bf16, bf16, 16, 16, 64, 64, 1, 8><<<NN * BB * 8, 256, 0, stream>>>(a0, coef0, wt1, a1, A1);
        coeffin_ker<16, 4096><<<1, 256, 0, stream>>>(A1, shw2, coef1);
        conv_ker<bf16, bf16, 16, 32, 64, 32, 2, 4><<<NN * BB * 8, 256, 0, stream>>>(a1, coef1, wt2, a2, A2);
        coeffin_ker<32, 1024><<<2, 256, 0, stream>>>(A2, shw3, coef2);
        conv_ker<bf16, float, 32, 32, 32, 32, 1, 8><<<NN * BB * 4, 256, 0, stream>>>(a2, coef2, wt3, a3, A3);
        coeffin_ker<32, 1024><<<2, 256, 0, stream>>>(A3, shw4, coef3);
        conv_ker<float, float, 32, 64, 32, 16, 2, 4><<<NN * BB * 4, 256, 0, stream>>>(a3, coef3, wt4, a4, A4);
        coeffin_ker<64, 256><<<4, 256, 0, stream>>>(A4, shw5, coef4);
        conv_ker<float, float, 64, 64, 16, 16, 1, 8><<<NN * BB * 2, 256, 0, stream>>>(a4, coef4, wt5, a5, A5);
        coeffin_ker<64, 256><<<4, 256, 0, stream>>>(A5, spool, coef5);
        pool_ker<float><<<NN * BB, 256, 0, stream>>>(a5, coef5, y);
    }

    bn1_ker<<<NN, 256, 0, stream>>>(y, sg, sb, yt);
    oghead_ker<<<256, 256, 0, stream>>>(yt, slin_w, slin_b, ograw);
    pred_ker<<<BB * NN, 256, 0, stream>>>(yt, sjig_w, sjig_b, d_out, flag);
    ogbn_ker<<<1, 256, 0, stream>>>(ograw, d_out, flag);
}

// Round 14
// 1610.693 us; speedup vs baseline: 1.0851x; 1.0851x over previous
//
#include <hip/hip_runtime.h>
#include <hip/hip_bf16.h>

typedef __hip_bfloat16 bf16;

#define BB 32   // batch
#define NN 16   // patches / backbones

__device__ __forceinline__ float b2f(bf16 v){ return __bfloat162float(v); }
__device__ __forceinline__ bf16  f2b(float v){ return __float2bfloat16(v); }
__device__ __forceinline__ float ldv(const float* p){ return *p; }
__device__ __forceinline__ float ldv(const bf16* p){ return b2f(*p); }
__device__ __forceinline__ void  stv(float* p, float v){ *p = v; }
__device__ __forceinline__ void  stv(bf16* p, float v){ *p = f2b(v); }

__device__ __forceinline__ float bfbits2f(unsigned int h){
    unsigned int x = h << 16; float f; __builtin_memcpy(&f, &x, 4); return f;
}
__device__ __forceinline__ float4 ldv4(const float* p){ return *(const float4*)p; }
__device__ __forceinline__ float4 ldv4(const bf16* p){
    uint2 u = *(const uint2*)p;
    float4 r;
    r.x = bfbits2f(u.x & 0xffffu);  r.y = bfbits2f(u.x >> 16);
    r.z = bfbits2f(u.y & 0xffffu);  r.w = bfbits2f(u.y >> 16);
    return r;
}

// ---------------------------------------------------------------------------
// dtype probe: flag=1 -> float32 inputs; 0 -> bf16.
// ---------------------------------------------------------------------------
__launch_bounds__(256)
__global__ void detect_ker(const unsigned short* __restrict__ xs, int* __restrict__ flag)
{
    int tid = threadIdx.x;
    int cnt = 0;
    for (int i = tid; i < 262144; i += 256) {
        unsigned short u = xs[i];
        if ((u & 0x7F80u) == 0x7F80u) cnt++;
    }
    #pragma unroll
    for (int off = 32; off > 0; off >>= 1) cnt += __shfl_down(cnt, off, 64);
    __shared__ int red[4];
    if ((tid & 63) == 0) red[tid >> 6] = cnt;
    __syncthreads();
    if (tid == 0) flag[0] = (red[0] + red[1] + red[2] + red[3]) > 0 ? 1 : 0;
}

// ---------------------------------------------------------------------------
// stage all inputs into a contiguous FLOAT arena
// ---------------------------------------------------------------------------
struct CvtArgs { const void* src[19]; int cnt[19]; int off[19]; };

__launch_bounds__(256)
__global__ void convert_ker(CvtArgs a, float* __restrict__ dst, const int* __restrict__ flag)
{
    const int which = blockIdx.y;
    const int cnt = a.cnt[which];
    if ((int)blockIdx.x * 2048 >= cnt) return;
    const int base = blockIdx.x * 2048 + threadIdx.x;
    float* d = dst + a.off[which];
    if (*flag) {
        const float* s = (const float*)a.src[which];
        #pragma unroll
        for (int k = 0; k < 8; ++k) { int j = base + k * 256; if (j < cnt) d[j] = s[j]; }
    } else {
        const bf16* s = (const bf16*)a.src[which];
        #pragma unroll
        for (int k = 0; k < 8; ++k) { int j = base + k * 256; if (j < cnt) d[j] = b2f(s[j]); }
    }
}

// ---------------------------------------------------------------------------
// single-launch weight transpose for all 5 conv stages:
// [n][co][ci][9] -> [n][ci*9+j][co]
// ---------------------------------------------------------------------------
struct WtArgs { const float* src[5]; float* dst[5]; int cout[5]; int cin[5]; };

__launch_bounds__(256)
__global__ void wtransall_ker(WtArgs a)
{
    const int which = blockIdx.y;
    const int cout = a.cout[which], cin = a.cin[which];
    const int per_n = cout * cin * 9;
    int i = blockIdx.x * 256 + threadIdx.x;
    if (i >= NN * per_n) return;
    int n = i / per_n, r = i - n * per_n;
    int co = r / (cin * 9), k = r - co * (cin * 9);
    a.dst[which][(size_t)n * per_n + k * cout + co] = a.src[which][i];
}

// ---------------------------------------------------------------------------
// conv0: x -> a0 (bf16, written ONCE) + per-channel sum/sumsq atomics (f32).
// ---------------------------------------------------------------------------
__launch_bounds__(256)
__global__ void conv0w_ker(const float* __restrict__ x, const float* __restrict__ w,
                           bf16* __restrict__ a0, float* __restrict__ accum)
{
    constexpr int STRIP = 8, STRIPS = 8, IN_ROWS = 10, TW = 66;
    __shared__ float tile[3][IN_ROWS][TW];
    const int tid = threadIdx.x;
    const int bid = blockIdx.x;
    const int s = bid % STRIPS;
    const int b = (bid / STRIPS) % BB;
    const int n = bid / (STRIPS * BB);
    const int pr = (n >> 2) * 64, pc = (n & 3) * 64;
    const int r0 = s * STRIP - 1;

    for (int idx = tid; idx < 3 * IN_ROWS * TW; idx += 256) {
        int ci = idx / (IN_ROWS * TW);
        int rem = idx - ci * (IN_ROWS * TW);
        int rr = rem / TW, cc = rem - rr * TW;
        int gr = r0 + rr, gc = cc - 1;
        float v = 0.f;
        if (gr >= 0 && gr < 64 && gc >= 0 && gc < 64)
            v = x[((size_t)(b * 3 + ci) * 256 + (pr + gr)) * 256 + (pc + gc)];
        tile[ci][rr][cc] = v;
    }
    __syncthreads();

    const int xo = tid & 63;
    const int wv = tid >> 6;
    for (int pass = 0; pass < 2; ++pass) {
        const int co = (pass * 4 + wv) * 2;
        const float* wb = w + (size_t)((n * 16 + co) * 3) * 9;
        float acc0[STRIP], acc1[STRIP];
        #pragma unroll
        for (int r = 0; r < STRIP; ++r) { acc0[r] = 0.f; acc1[r] = 0.f; }
        #pragma unroll
        for (int ci = 0; ci < 3; ++ci) {
            float w0[9], w1[9];
            #pragma unroll
            for (int j = 0; j < 9; ++j) {
                w0[j] = wb[ci * 9 + j];
                w1[j] = wb[(3 + ci) * 9 + j];
            }
            float win[3][3];
            #pragma unroll
            for (int c0 = 0; c0 < 3; ++c0) {
                win[0][c0] = tile[ci][0][xo + c0];
                win[1][c0] = tile[ci][1][xo + c0];
            }
            #pragma unroll
            for (int ry = 0; ry < STRIP; ++ry) {
                #pragma unroll
                for (int c0 = 0; c0 < 3; ++c0)
                    win[(ry + 2) % 3][c0] = tile[ci][ry + 2][xo + c0];
                #pragma unroll
                for (int ky = 0; ky < 3; ++ky)
                    #pragma unroll
                    for (int kx = 0; kx < 3; ++kx) {
                        float v = win[(ry + ky) % 3][kx];
                        acc0[ry] = fmaf(v, w0[ky * 3 + kx], acc0[ry]);
                        acc1[ry] = fmaf(v, w1[ky * 3 + kx], acc1[ry]);
                    }
            }
        }
        bf16* ob = a0 + (size_t)((n * BB + b) * 16 + co) * 4096 + (s * STRIP) * 64 + xo;
        float s0 = 0.f, q0 = 0.f, s1 = 0.f, q1 = 0.f;
        #pragma unroll
        for (int r = 0; r < STRIP; ++r) {
            ob[r * 64] = f2b(acc0[r]);
            ob[4096 + r * 64] = f2b(acc1[r]);
            s0 += acc0[r]; q0 = fmaf(acc0[r], acc0[r], q0);
            s1 += acc1[r]; q1 = fmaf(acc1[r], acc1[r], q1);
        }
        #pragma unroll
        for (int off = 32; off > 0; off >>= 1) {
            s0 += __shfl_down(s0, off, 64); q0 += __shfl_down(q0, off, 64);
            s1 += __shfl_down(s1, off, 64); q1 += __shfl_down(q1, off, 64);
        }
        if (xo == 0) {
            atomicAdd(&accum[n * 16 + co],       s0);
            atomicAdd(&accum[256 + n * 16 + co], q0);
            atomicAdd(&accum[n * 16 + co + 1],       s1);
            atomicAdd(&accum[256 + n * 16 + co + 1], q1);
        }
    }
}

// ---------------------------------------------------------------------------
// generic coef finalize
// ---------------------------------------------------------------------------
template<int C, int HW>
__launch_bounds__(256)
__global__ void coeffin_ker(const float* __restrict__ accum, const float* __restrict__ hw,
                            float* __restrict__ coef)
{
    int i = blockIdx.x * 256 + threadIdx.x;   // n*C+c
    if (i >= NN * C) return;
    const float cnt = (float)(BB * HW);
    float mu = accum[i] / cnt;
    float var = fmaxf(accum[NN * C + i] / cnt - mu * mu, 0.f);
    float rs = rsqrtf(var + 1e-5f);
    int n = i / C, c = i - n * C;
    float w0 = hw[(n * 3 + 0) * C + c];
    float w1 = hw[(n * 3 + 1) * C + c];
    float w2 = hw[(n * 3 + 2) * C + c];
    float c2 = w2 * 0.70710678118654752440f;
    coef[i * 3 + 0] = (w0 - c2) - w1 * rs * mu + c2 * rs * rs * mu * mu;
    coef[i * 3 + 1] = w1 * rs - 2.f * c2 * rs * rs * mu;
    coef[i * 3 + 2] = c2 * rs * rs;
}

// ---------------------------------------------------------------------------
// generic fused herpn+conv3x3 (R12 layout/mapping, conflict-free):
//  - compact halo layout: row stride S=WIN+4, left halo at slot+3,
//    interior 16B-aligned, right halo in next slot's element 0.
//  - vectorized float4 staging with herpn in-register
//  - software-pipelined transposed weights (2 register buffers)
//  - NEW: LDS window prefetched one iteration ahead (4-row ring for s1,
//    ping-pong 9-elem buffer for s2) to hide ds_read latency
//  - TCO=4, fused stats epilogue
// ---------------------------------------------------------------------------
template<typename TI, typename TO, int CIN, int COUT, int WIN, int WOUT, int STRIDE, int STRIP>
__launch_bounds__(256)
__global__ void conv_ker(const TI* __restrict__ ain, const float* __restrict__ coef,
                         const float* __restrict__ wT, TO* __restrict__ aout,
                         float* __restrict__ accum)
{
    constexpr int HIN = WIN, HOUT = WOUT;
    constexpr int STRIPS = HOUT / STRIP;
    constexpr int IN_ROWS = STRIDE * (STRIP - 1) + 3;
    constexpr int S = WIN + 4;               // compact row stride
    constexpr int CQ = 256 / WOUT;
    constexpr int TCO = 4;
    constexpr int L = WIN / 4;               // float4 chunks per row
    constexpr int RPI = 256 / L;             // rows staged per iteration
    constexpr int NROWS = CIN * IN_ROWS;
    static_assert(CQ * TCO == COUT, "single pass covers all channels");
    static_assert(NROWS % RPI == 0, "staging divides evenly");

    __shared__ float tile[NROWS * S + 4];
    __shared__ float cfA[CIN], cfB[CIN], cfC[CIN];

    const int tid = threadIdx.x;
    const int bid = blockIdx.x;
    const int s = bid % STRIPS;
    const int b = (bid / STRIPS) % BB;
    const int n = bid / (STRIPS * BB);

    if (tid < CIN) {
        cfA[tid] = coef[(n * CIN + tid) * 3 + 0];
        cfB[tid] = coef[(n * CIN + tid) * 3 + 1];
        cfC[tid] = coef[(n * CIN + tid) * 3 + 2];
    }
    __syncthreads();

    const int r0 = s * STRIP * STRIDE - 1;
    const TI* abase = ain + (size_t)(n * BB + b) * CIN * HIN * WIN;

    // halo zero
    for (int h = tid; h < NROWS * 2 + 1; h += 256) {
        if (h == NROWS * 2) tile[NROWS * S] = 0.f;
        else tile[(h >> 1) * S + ((h & 1) ? 3 : 0)] = 0.f;
    }
    // vectorized interior staging
    {
        const int li = tid % L;
        const int rs0 = tid / L;
        #pragma unroll
        for (int it = 0; it < NROWS / RPI; ++it) {
            int rslot = rs0 + it * RPI;
            int ci = rslot / IN_ROWS;
            int rr = rslot - ci * IN_ROWS;
            int gr = r0 + rr;
            float4 v = {0.f, 0.f, 0.f, 0.f};
            if (gr >= 0 && gr < HIN) {
                v = ldv4(&abase[(size_t)ci * HIN * WIN + gr * WIN + li * 4]);
                float Aq = cfA[ci], Bq = cfB[ci], Cq = cfC[ci];
                v.x = fmaf(v.x, fmaf(v.x, Cq, Bq), Aq);
                v.y = fmaf(v.y, fmaf(v.y, Cq, Bq), Aq);
                v.z = fmaf(v.z, fmaf(v.z, Cq, Bq), Aq);
                v.w = fmaf(v.w, fmaf(v.w, Cq, Bq), Aq);
            }
            *(float4*)&tile[rslot * S + 4 + li * 4] = v;
        }
    }
    __syncthreads();

    const int xo = tid % WOUT;
    const int cq = tid / WOUT;
    const float4* wb4 = (const float4*)(wT + (size_t)n * (CIN * 9 * COUT));
    float acc[TCO][STRIP];
    #pragma unroll
    for (int t = 0; t < TCO; ++t)
        #pragma unroll
        for (int r = 0; r < STRIP; ++r) acc[t][r] = 0.f;

    auto conv_ci = [&](int ci, const float4 (&wq)[9]) {
        const float* wf = (const float*)&wq[0];   // wf[j*4+t]
        const float* tci = &tile[ci * IN_ROWS * S];
        if (STRIDE == 1) {
            // 4-row ring buffer: row ry+3 prefetched while computing row ry
            float win[4][3];
            #pragma unroll
            for (int r = 0; r < 3; ++r)
                #pragma unroll
                for (int c0 = 0; c0 < 3; ++c0)
                    win[r][c0] = tci[r * S + 3 + xo + c0];
            #pragma unroll
            for (int ry = 0; ry < STRIP; ++ry) {
                if (ry + 3 < IN_ROWS) {
                    #pragma unroll
                    for (int c0 = 0; c0 < 3; ++c0)
                        win[(ry + 3) & 3][c0] = tci[(ry + 3) * S + 3 + xo + c0];
                }
                #pragma unroll
                for (int ky = 0; ky < 3; ++ky)
                    #pragma unroll
                    for (int kx = 0; kx < 3; ++kx) {
                        float v = win[(ry + ky) & 3][kx];
                        #pragma unroll
                        for (int t = 0; t < TCO; ++t)
                            acc[t][ry] = fmaf(v, wf[(ky * 3 + kx) * 4 + t], acc[t][ry]);
                    }
            }
        } else {
            // ping-pong 9-elem window: row-group ry+1 prefetched during ry
            float e[2][9];
            #pragma unroll
            for (int k = 0; k < 9; ++k)
                e[0][k] = tci[(k / 3) * S + 3 + xo * 2 + (k % 3)];
            #pragma unroll
            for (int ry = 0; ry < STRIP; ++ry) {
                if (ry + 1 < STRIP) {
                    #pragma unroll
                    for (int k = 0; k < 9; ++k)
                        e[(ry + 1) & 1][k] = tci[((ry + 1) * 2 + k / 3) * S + 3 + xo * 2 + (k % 3)];
                }
                #pragma unroll
                for (int j = 0; j < 9; ++j) {
                    float v = e[ry & 1][j];
                    #pragma unroll
                    for (int t = 0; t < TCO; ++t)
                        acc[t][ry] = fmaf(v, wf[j * 4 + t], acc[t][ry]);
                }
            }
        }
    };

    // software-pipelined weight loads (2 register buffers)
    float4 wqA[9], wqB[9];
    #pragma unroll
    for (int j = 0; j < 9; ++j) wqA[j] = wb4[j * (COUT / 4) + cq];
    for (int ci = 0; ci < CIN; ci += 2) {
        #pragma unroll
        for (int j = 0; j < 9; ++j) wqB[j] = wb4[((ci + 1) * 9 + j) * (COUT / 4) + cq];
        conv_ci(ci, wqA);
        if (ci + 2 < CIN) {
            #pragma unroll
            for (int j = 0; j < 9; ++j) wqA[j] = wb4[((ci + 2) * 9 + j) * (COUT / 4) + cq];
        }
        conv_ci(ci + 1, wqB);
    }

    const int co = cq * TCO;
    #pragma unroll
    for (int t = 0; t < TCO; ++t) {
        TO* ob = aout + (size_t)((n * BB + b) * COUT + co + t) * HOUT * WOUT
                 + (s * STRIP) * WOUT + xo;
        float ps = 0.f, pq = 0.f;
        #pragma unroll
        for (int r = 0; r < STRIP; ++r) {
            stv(&ob[r * WOUT], acc[t][r]);
            ps += acc[t][r]; pq = fmaf(acc[t][r], acc[t][r], pq);
        }
        #pragma unroll
        for (int off = WOUT / 2; off > 0; off >>= 1) {
            ps += __shfl_down(ps, off, WOUT); pq += __shfl_down(pq, off, WOUT);
        }
        if (xo == 0) {
            atomicAdd(&accum[n * COUT + co + t], ps);
            atomicAdd(&accum[NN * COUT + n * COUT + co + t], pq);
        }
    }
}

// ---------------------------------------------------------------------------
// pool: herpn(a5) -> quadrant means -> y[N,B,256] (fp32)
// ---------------------------------------------------------------------------
template<typename TI>
__launch_bounds__(256)
__global__ void pool_ker(const TI* __restrict__ a5, const float* __restrict__ coef,
                         float* __restrict__ y)
{
    const int n = blockIdx.x / BB, b = blockIdx.x % BB;
    const int f = threadIdx.x;
    const int c = f >> 2, qh = (f >> 1) & 1, qw = f & 1;
    const TI* p = a5 + (size_t)((n * BB + b) * 64 + c) * 256;
    float A = coef[(n * 64 + c) * 3 + 0];
    float Bc = coef[(n * 64 + c) * 3 + 1];
    float Cc = coef[(n * 64 + c) * 3 + 2];
    float ssum = 0.f;
    for (int iy = 0; iy < 8; ++iy)
        for (int ix = 0; ix < 8; ++ix) {
            float raw = ldv(&p[(qh * 8 + iy) * 16 + (qw * 8 + ix)]);
            ssum += fmaf(raw, fmaf(raw, Cc, Bc), A);
        }
    y[(size_t)(n * BB + b) * 256 + f] = ssum * (1.f / 64.f);
}

// ---------------------------------------------------------------------------
// bn1: per (n,f) BN over B; writes batch-major yt[B][4096]
// ---------------------------------------------------------------------------
__launch_bounds__(256)
__global__ void bn1_ker(const float* __restrict__ y, const float* __restrict__ g,
                        const float* __restrict__ bta, float* __restrict__ yt)
{
    const int gid = blockIdx.x * 256 + threadIdx.x;   // n*256 + f
    const int n = gid >> 8;
    float s = 0.f, s2 = 0.f;
    for (int b = 0; b < BB; ++b) {
        float v = y[(size_t)((n * BB + b) * 256) + (gid & 255)];
        s += v;
        s2 = fmaf(v, v, s2);
    }
    float mu = s * (1.f / BB);
    float var = fmaxf(s2 * (1.f / BB) - mu * mu, 0.f);
    float rs = rsqrtf(var + 1e-5f);
    float gg = g[gid];
    float bb = bta[gid];
    for (int b = 0; b < BB; ++b) {
        float v = y[(size_t)((n * BB + b) * 256) + (gid & 255)];
        yt[(size_t)b * 4096 + gid] = fmaf((v - mu) * rs, gg, bb);
    }
}

// ---------------------------------------------------------------------------
// og head + fused og-BN + target write. Block j computes column j for all
// 32 batches, then normalizes over the batch in-block.
// ---------------------------------------------------------------------------
__launch_bounds__(256)
__global__ void oghead_ker(const float* __restrict__ yt, const float* __restrict__ lin_w,
                           const float* __restrict__ lin_b, void* __restrict__ d_out,
                           const int* __restrict__ flag)
{
    __shared__ float sw[4096];
    __shared__ float col[BB];
    const int j = blockIdx.x;
    const float* wrow = lin_w + (size_t)j * 4096;
    for (int i = threadIdx.x; i < 4096; i += 256) sw[i] = wrow[i];
    __syncthreads();
    const int wv = threadIdx.x >> 6, ln = threadIdx.x & 63;
    const float bj = lin_b[j];
    for (int b = wv; b < BB; b += 4) {
        const float* yr = yt + (size_t)b * 4096;
        float a = 0.f;
        for (int i = ln; i < 4096; i += 64)
            a = fmaf(yr[i], sw[i], a);
        #pragma unroll
        for (int off = 32; off > 0; off >>= 1) a += __shfl_down(a, off, 64);
        if (ln == 0) col[b] = a + bj;
    }
    __syncthreads();
    if (threadIdx.x < 32) {
        float v = col[threadIdx.x];
        float sum = v, sq = v * v;
        #pragma unroll
        for (int off = 16; off > 0; off >>= 1) {
            sum += __shfl_down(sum, off, 32);
            sq  += __shfl_down(sq, off, 32);
        }
        float mu = __shfl(sum, 0, 32) * (1.f / BB);
        float var = fmaxf(__shfl(sq, 0, 32) * (1.f / BB) - mu * mu, 0.f);
        float rs = rsqrtf(var + 1e-5f);
        float o = (v - mu) * rs;
        const bool isf32 = (*flag != 0);
        if (isf32) ((float*)d_out)[threadIdx.x * 256 + j] = o;
        else       ((bf16*)d_out)[threadIdx.x * 256 + j] = f2b(o);
        if (threadIdx.x == 0) {
            float t = (float)(j & 15);
            if (isf32) { ((float*)d_out)[16384 + j] = t; ((float*)d_out)[16640 + j] = t; }
            else       { ((bf16*)d_out)[16384 + j] = f2b(t); ((bf16*)d_out)[16640 + j] = f2b(t); }
        }
    }
}

// ---------------------------------------------------------------------------
// pred head
// ---------------------------------------------------------------------------
__launch_bounds__(256)
__global__ void pred_ker(const float* __restrict__ yt, const float* __restrict__ jig_w,
                         const float* __restrict__ jig_b, void* __restrict__ d_out,
                         const int* __restrict__ flag)
{
    __shared__ float sy[256];
    const int b = blockIdx.x >> 4, n = blockIdx.x & 15;
    sy[threadIdx.x] = yt[(size_t)b * 4096 + n * 256 + threadIdx.x];
    __syncthreads();
    const int k = threadIdx.x >> 4, part = threadIdx.x & 15;
    const float* wrow = jig_w + k * 256 + part * 16;
    const float* srow = sy + part * 16;
    float p = 0.f;
    #pragma unroll
    for (int t = 0; t < 16; ++t) p = fmaf(srow[t], wrow[t], p);
    #pragma unroll
    for (int off = 8; off > 0; off >>= 1) p += __shfl_down(p, off, 16);
    if (part == 0) {
        float v = p + jig_b[k];
        int pidx = 8192 + (b * 16 + n) * 16 + k;
        if (*flag) ((float*)d_out)[pidx] = v;
        else       ((bf16*)d_out)[pidx] = f2b(v);
    }
}

// ---------------------------------------------------------------------------
extern "C" void kernel_launch(void* const* d_in, const int* in_sizes, int n_in,
                              void* d_out, int out_size, void* d_ws, size_t ws_size,
                              hipStream_t stream)
{
    char* wsb = (char*)d_ws;
    int*   flag   = (int*)wsb;                      // @0
    float* accumZ = (float*)(wsb + 4096);           // 7168 f stats accumulators
    float* coefs  = (float*)(wsb + 36864);          // 6*3072 f
    float* y      = (float*)(wsb + 131072);         // 131072 f
    float* yt     = (float*)(wsb + 655360);         // 131072 f  [B][4096]
    float* wTall  = (float*)(wsb + 1310720);        // transposed weights
    float* staged = (float*)(wsb + 6029312);        // f32 arena

    float* A0 = accumZ + 0;      // 512  (16ch)
    float* A1 = accumZ + 512;    // 512  (16ch)
    float* A2 = accumZ + 1024;   // 1024 (32ch)
    float* A3 = accumZ + 2048;   // 1024 (32ch)
    float* A4 = accumZ + 3072;   // 2048 (64ch)
    float* A5 = accumZ + 5120;   // 2048 (64ch)

    float* wt1 = wTall;                 // 16*2304
    float* wt2 = wt1 + 36864;           // 16*4608
    float* wt3 = wt2 + 73728;           // 16*9216
    float* wt4 = wt3 + 147456;          // 16*18432
    float* wt5 = wt4 + 294912;          // 16*36864

    CvtArgs ca;
    int off = 0, maxc = 0;
    for (int i = 0; i < 19; ++i) {
        ca.src[i] = d_in[i];
        ca.cnt[i] = in_sizes[i];
        ca.off[i] = off;
        off += in_sizes[i];
        if (in_sizes[i] > maxc) maxc = in_sizes[i];
    }
    float* sx      = staged + ca.off[0];
    float* scw0    = staged + ca.off[1];
    float* shw1    = staged + ca.off[2];
    float* scw1    = staged + ca.off[3];
    float* shw2    = staged + ca.off[4];
    float* scw2    = staged + ca.off[5];
    float* shw3    = staged + ca.off[6];
    float* scw3    = staged + ca.off[7];
    float* shw4    = staged + ca.off[8];
    float* scw4    = staged + ca.off[9];
    float* shw5    = staged + ca.off[10];
    float* scw5    = staged + ca.off[11];
    float* spool   = staged + ca.off[12];
    float* sg      = staged + ca.off[13];
    float* sb      = staged + ca.off[14];
    float* slin_w  = staged + ca.off[15];
    float* slin_b  = staged + ca.off[16];
    float* sjig_w  = staged + ca.off[17];
    float* sjig_b  = staged + ca.off[18];

    float* coef0 = coefs + 0 * 3072;
    float* coef1 = coefs + 1 * 3072;
    float* coef2 = coefs + 2 * 3072;
    float* coef3 = coefs + 3 * 3072;
    float* coef4 = coefs + 4 * 3072;
    float* coef5 = coefs + 5 * 3072;

    size_t stagedEnd = 6029312ull + (size_t)off * 4ull;
    size_t r1off = (stagedEnd + (1ull << 20)) & ~((1ull << 20) - 1ull);
    const bool planA = ws_size >= r1off + (128ull << 20) + (64ull << 20);

    detect_ker<<<1, 256, 0, stream>>>((const unsigned short*)d_in[0], flag);
    convert_ker<<<dim3((maxc + 2047) / 2048, 19), 256, 0, stream>>>(ca, staged, flag);

    WtArgs wa;
    wa.src[0] = scw1; wa.dst[0] = wt1; wa.cout[0] = 16; wa.cin[0] = 16;
    wa.src[1] = scw2; wa.dst[1] = wt2; wa.cout[1] = 32; wa.cin[1] = 16;
    wa.src[2] = scw3; wa.dst[2] = wt3; wa.cout[2] = 32; wa.cin[2] = 32;
    wa.src[3] = scw4; wa.dst[3] = wt4; wa.cout[3] = 64; wa.cin[3] = 32;
    wa.src[4] = scw5; wa.dst[4] = wt5; wa.cout[4] = 64; wa.cin[4] = 64;
    wtransall_ker<<<dim3(2304, 5), 256, 0, stream>>>(wa);

    hipMemsetAsync(accumZ, 0, 7168 * sizeof(float), stream);

    if (planA) {
        float* rA = (float*)(wsb + r1off);
        char*  rB = wsb + r1off + (128ull << 20);
        bf16*  a0 = (bf16*)rB;          // 64 MiB
        float* a1 = rA;                 // 128 MiB
        float* a2 = (float*)rB;         // 64 MiB (a0 dead after conv1)
        float* a3 = rA;
        float* a4 = (float*)rB;
        float* a5 = rA;

        conv0w_ker<<<NN * BB * 8, 256, 0, stream>>>(sx, scw0, a0, A0);
        coeffin_ker<16, 4096><<<1, 256, 0, stream>>>(A0, shw1, coef0);
        conv_ker<bf16, float, 16, 16, 64, 64, 1, 8><<<NN * BB * 8, 256, 0, stream>>>(a0, coef0, wt1, a1, A1);
        coeffin_ker<16, 4096><<<1, 256, 0, stream>>>(A1, shw2, coef1);
        conv_ker<float, float, 16, 32, 64, 32, 2, 4><<<NN * BB * 8, 256, 0, stream>>>(a1, coef1, wt2, a2, A2);
        coeffin_ker<32, 1024><<<2, 256, 0, stream>>>(A2, shw3, coef2);
        conv_ker<float, float, 32, 32, 32, 32, 1, 8><<<NN * BB * 4, 256, 0, stream>>>(a2, coef2, wt3, a3, A3);
        coeffin_ker<32, 1024><<<2, 256, 0, stream>>>(A3, shw4, coef3);
        conv_ker<float, float, 32, 64, 32, 16, 2, 4><<<NN * BB * 4, 256, 0, stream>>>(a3, coef3, wt4, a4, A4);
        coeffin_ker<64, 256><<<4, 256, 0, stream>>>(A4, shw5, coef4);
        conv_ker<float, float, 64, 64, 16, 16, 1, 8><<<NN * BB * 2, 256, 0, stream>>>(a4, coef4, wt5, a5, A5);
        coeffin_ker<64, 256><<<4, 256, 0, stream>>>(A5, spool, coef5);
        pool_ker<float><<<NN * BB, 256, 0, stream>>>(a5, coef5, y);
    } else {
        char* rA = wsb + r1off;
        char* rB = wsb + r1off + (64ull << 20);
        bf16*  a0 = (bf16*)rB;
        bf16*  a1 = (bf16*)rA;
        bf16*  a2 = (bf16*)rB;
        float* a3 = (float*)rA;
        float* a4 = (float*)rB;
        float* a5 = (float*)rA;

        conv0w_ker<<<NN * BB * 8, 256, 0, stream>>>(sx, scw0, a0, A0);
        coeffin_ker<16, 4096><<<1, 256, 0, stream>>>(A0, shw1, coef0);
        conv_ker<bf16, bf16, 16, 16, 64, 64, 1, 8><<<NN * BB * 8, 256, 0, stream>>>(a0, coef0, wt1, a1, A1);
        coeffin_ker<16, 4096><<<1, 256, 0, stream>>>(A1, shw2, coef1);
        conv_ker<bf16, bf16, 16, 32, 64, 32, 2, 4><<<NN * BB * 8, 256, 0, stream>>>(a1, coef1, wt2, a2, A2);
        coeffin_ker<32, 1024><<<2, 256, 0, stream>>>(A2, shw3, coef2);
        conv_ker<bf16, float, 32, 32, 32, 32, 1, 8><<<NN * BB * 4, 256, 0, stream>>>(a2, coef2, wt3, a3, A3);
        coeffin_ker<32, 1024><<<2, 256, 0, stream>>>(A3, shw4, coef3);
        conv_ker<float, float, 32, 64, 32, 16, 2, 4><<<NN * BB * 4, 256, 0, stream>>>(a3, coef3, wt4, a4, A4);
        coeffin_ker<64, 256><<<4, 256, 0, stream>>>(A4, shw5, coef4);
        conv_ker<float, float, 64, 64, 16, 16, 1, 8><<<NN * BB * 2, 256, 0, stream>>>(a4, coef4, wt5, a5, A5);
        coeffin_ker<64, 256><<<4, 256, 0, stream>>>(A5, spool, coef5);
        pool_ker<float><<<NN * BB, 256, 0, stream>>>(a5, coef5, y);
    }

    bn1_ker<<<NN, 256, 0, stream>>>(y, sg, sb, yt);
    oghead_ker<<<256, 256, 0, stream>>>(yt, slin_w, slin_b, d_out, flag);
    pred_ker<<<BB * NN, 256, 0, stream>>>(yt, sjig_w, sjig_b, d_out, flag);
}